// Round 4
// baseline (546.228 us; speedup 1.0000x reference)
//
#include <hip/hip_runtime.h>
#include <hip/hip_bf16.h>

// ---------------------------------------------------------------------------
// ResidualSAGEBlock: block-private bucket sort -> CSR(+offs) -> bf16 gather ->
// MFMA bf16 dual GEMM (+in-kernel BN stats) -> finalize(BN+res+ReLU).
// N=100000, D=128, E=1600000.
// R2: CSR gather replaced float-atomic scatter: 3095->812us.
// R7: 3-pass block-private counting sort: 757->409us.
// R8: bf16 gather source; offs folded into csrbuild; packed pairs: 409->306us.
// R10: bf16 h; bf16 residual; bnparam folded into finalize: 306->303us.
// R11: 12->9 dispatches; in-mfma stat atomics: 303->296us.
// R12: 32-way replicated stats: 296->290us. gather FETCH=177MB = per-XCD
//      L2-miss replication floor at full-row granularity.
// R13 FAILED: gather fused into mfma: 782-block grid underfills (occ 19%,
//      fetch 3.6->1.6TB/s): 290->316us. Reverted.
// R14 NEUTRAL: pk-f32 accumulate, buckets 128, prep merged: 291.9us.
//      Gather NOT VALU-limited; time == FETCH / 3.2TB/s (L2-miss path).
// R15 FAILED: column-quarter with ASSUMED blockIdx%8->XCD map: FETCH
//      177->304MB (= no-affinity model) -> the %8 map does NOT hold.
//      Also 64B quarters waste half of each 128B line.
// R16: TRUE XCD affinity: read HW_REG_XCC_ID, block picks column HALF
//      (128B = one L2 line) = xcc&1 via two atomic work queues (overflow
//      fallback keeps assignment exact). Per-XCD xb miss footprint
//      22MB->12.8MB. Predicted FETCH ~120MB, gather ~40us.
// ---------------------------------------------------------------------------

#define D128 128
#define BSH2 7          // log2(nodes per bucket)
#define BSZ2 128        // nodes per bucket
#define MAXBUK 1024     // LDS bound for buckets (NBUK=782 actual)
#define SBLK 256        // sort blocks
#define CAP  2816       // csrbuild LDS capacity (mean 2048, +17 sigma)
#define SREP 32         // stat replicas

typedef short bf16x8 __attribute__((ext_vector_type(8)));
typedef float f32x4  __attribute__((ext_vector_type(4)));
typedef float f32x2  __attribute__((ext_vector_type(2)));

static __device__ __forceinline__ unsigned short f2bf(float f) {
    unsigned u = __builtin_bit_cast(unsigned, f);
    unsigned r = u + 0x7fffu + ((u >> 16) & 1u);   // round-to-nearest-even
    return (unsigned short)(r >> 16);
}
static __device__ __forceinline__ float bflo(unsigned u) {   // low bf16 -> f32
    return __builtin_bit_cast(float, u << 16);
}
static __device__ __forceinline__ float bfhi(unsigned u) {   // high bf16 -> f32
    return __builtin_bit_cast(float, u & 0xffff0000u);
}
static __device__ __forceinline__ f32x2 bf2(unsigned u) {    // {lo,hi} pair
    f32x2 r;
    r.x = bflo(u);
    r.y = bfhi(u);
    return r;
}

// --- sort pass 1: per-block bucket histogram + fused x->bf16 conversion ----
// Blocks 0..15 additionally build swizzled bf16 B for MFMA and zero the
// replicated stats; block 16 zeroes the gather work queues.
//   Bsw[t][c][lane][j] = Wcat[t*32 + (lane>>4)*8 + j][c*16 + (lane&15)]
//   Wcat[k][d] = k<128 ? Wl[d][k] : Wr[d][k-128].
__global__ __launch_bounds__(256) void bhist_kernel(
    const int* __restrict__ dst, int* __restrict__ ghist,
    const float* __restrict__ x, unsigned short* __restrict__ xb,
    const float* __restrict__ Wl, const float* __restrict__ Wr,
    unsigned short* __restrict__ Bsw, float* __restrict__ stats,
    int* __restrict__ queue,
    int E, int chunk, int NBUK, int total4) {
    __shared__ int lh[MAXBUK];
    int tid = threadIdx.x;
    int b   = blockIdx.x;
    if (b < 16) {                       // merged prep work
        int idx = b * 256 + tid;        // 0..4095
        stats[idx] = 0.f;               // 2 x 4096 = SREP*256 floats
        stats[idx + 4096] = 0.f;
        int l = idx & 63;
        int c = (idx >> 6) & 7;
        int t = idx >> 9;
        int d = c * 16 + (l & 15);
        int kbase = t * 32 + (l >> 4) * 8;
        unsigned short o[8];
#pragma unroll
        for (int j = 0; j < 8; ++j) {
            int k = kbase + j;
            float v = (k < 128) ? Wl[d * 128 + k] : Wr[d * 128 + (k - 128)];
            o[j] = f2bf(v);
        }
        *(uint4*)(Bsw + (size_t)idx * 8) = *(const uint4*)o;
    } else if (b == 16 && tid < 2) {
        queue[tid] = 0;                 // gather work-queue heads
    }
    for (int i = tid; i < NBUK; i += 256) lh[i] = 0;
    __syncthreads();
    int beg = b * chunk;
    int end = min(beg + chunk, E);
    for (int i = beg + tid; i < end; i += 256)
        atomicAdd(&lh[dst[i] >> BSH2], 1);
    __syncthreads();
    for (int i = tid; i < NBUK; i += 256) ghist[i * SBLK + b] = lh[i];
    // fused streaming conversion x (fp32) -> xb (bf16)
    for (int i = b * 256 + tid; i < total4; i += 256 * SBLK) {
        float4 v = ((const float4*)x)[i];
        uint2 o;
        o.x = (unsigned)f2bf(v.x) | ((unsigned)f2bf(v.y) << 16);
        o.y = (unsigned)f2bf(v.z) | ((unsigned)f2bf(v.w) << 16);
        ((uint2*)xb)[i] = o;
    }
}

// --- scan stage 1: per-block (1024 elems) partial sums ---------------------
__global__ __launch_bounds__(256) void partial_kernel(const int* __restrict__ deg,
                                                      int* __restrict__ bsum, int N) {
    int tid  = threadIdx.x;
    int base = blockIdx.x * 1024 + tid * 4;
    int s = 0;
    if (base + 3 < N) {
        int4 v = *(const int4*)(deg + base);
        s = v.x + v.y + v.z + v.w;
    } else {
        for (int i = base; i < N; ++i) s += deg[i];
    }
    __shared__ int red[256];
    red[tid] = s;
    __syncthreads();
    for (int off = 128; off > 0; off >>= 1) {
        if (tid < off) red[tid] += red[tid + off];
        __syncthreads();
    }
    if (tid == 0) bsum[blockIdx.x] = red[0];
}

// --- scan stage 2 (final): per-block scan + redundant LDS scan of bsum -----
__global__ __launch_bounds__(256) void scan_final_kernel(
    const int* __restrict__ deg, const int* __restrict__ bsum,
    int* __restrict__ offs, int N, int NB2) {
    __shared__ int sb[2][256];
    int tid = threadIdx.x;
    int bv = (tid < NB2) ? bsum[tid] : 0;
    sb[0][tid] = bv;
    __syncthreads();
    int bpi = 0;
    for (int off = 1; off < 256; off <<= 1) {
        int u = sb[bpi][tid];
        if (tid >= off) u += sb[bpi][tid - off];
        sb[bpi ^ 1][tid] = u;
        __syncthreads();
        bpi ^= 1;
    }
    int ebsum = (blockIdx.x > 0) ? sb[bpi][blockIdx.x - 1] : 0;
    __syncthreads();

    int base = blockIdx.x * 1024 + tid * 4;
    int d0 = 0, d1 = 0, d2 = 0, d3 = 0;
    if (base + 3 < N) {
        int4 v = *(const int4*)(deg + base);
        d0 = v.x; d1 = v.y; d2 = v.z; d3 = v.w;
    } else {
        if (base     < N) d0 = deg[base];
        if (base + 1 < N) d1 = deg[base + 1];
        if (base + 2 < N) d2 = deg[base + 2];
        if (base + 3 < N) d3 = deg[base + 3];
    }
    int s = d0 + d1 + d2 + d3;
    sb[0][tid] = s;
    __syncthreads();
    int pi = 0;
    for (int off = 1; off < 256; off <<= 1) {
        int u = sb[pi][tid];
        if (tid >= off) u += sb[pi][tid - off];
        sb[pi ^ 1][tid] = u;
        __syncthreads();
        pi ^= 1;
    }
    int pre = sb[pi][tid] - s + ebsum;
    if (base + 3 < N) {
        int4 o = make_int4(pre, pre + d0, pre + d0 + d1, pre + d0 + d1 + d2);
        *(int4*)(offs + base) = o;
    } else {
        int p = pre;
        if (base     < N) { offs[base]     = p; p += d0; }
        if (base + 1 < N) { offs[base + 1] = p; p += d1; }
        if (base + 2 < N) { offs[base + 2] = p; p += d2; }
        if (base + 3 < N) { offs[base + 3] = p; }
    }
}

// --- sort pass 2: scatter packed (src<<8 | dst&255) into private ranges ----
__global__ __launch_bounds__(256) void bscatter_kernel(
    const int* __restrict__ src, const int* __restrict__ dst,
    const int* __restrict__ gsc, unsigned* __restrict__ pairs,
    int E, int chunk, int NBUK) {
    __shared__ int lcur[MAXBUK];
    int tid = threadIdx.x;
    int b   = blockIdx.x;
    for (int i = tid; i < NBUK; i += 256) lcur[i] = gsc[i * SBLK + b];
    __syncthreads();
    int beg = b * chunk;
    int end = min(beg + chunk, E);
    for (int i = beg + tid; i < end; i += 256) {
        int d = dst[i];
        int s = src[i];
        int pos = atomicAdd(&lcur[d >> BSH2], 1);
        pairs[pos] = ((unsigned)s << 8) | (unsigned)(d & 255);
    }
}

// --- per-bucket: local node histogram + scan -> offs; LDS sort -> csr ------
// BSZ2=128: counters 128..255 stay zero; 256-wide scan still yields correct
// exclusive prefixes, and pre[128] == len covers the offs[bucket_end] write.
__global__ __launch_bounds__(256) void csrbuild_kernel(
    const unsigned* __restrict__ pairs, const int* __restrict__ gsc,
    int* __restrict__ csr, int* __restrict__ offs, int N, int NBUK, int E) {
    __shared__ int lcnt[256];
    __shared__ int sbuf[2][256];
    __shared__ int lcsr[CAP];
    int b   = blockIdx.x;
    int tid = threadIdx.x;
    int nlo = b << BSH2;
    int base = gsc[(size_t)b * SBLK];                       // bucket start
    int end  = (b + 1 < NBUK) ? gsc[(size_t)(b + 1) * SBLK] : E;
    int len  = end - base;
    lcnt[tid] = 0;
    __syncthreads();
    for (int i = tid; i < len; i += 256)
        atomicAdd(&lcnt[pairs[base + i] & 127u], 1);
    __syncthreads();
    int c = lcnt[tid];
    sbuf[0][tid] = c;
    __syncthreads();
    int pi = 0;
    for (int off = 1; off < 256; off <<= 1) {
        int u = sbuf[pi][tid];
        if (tid >= off) u += sbuf[pi][tid - off];
        sbuf[pi ^ 1][tid] = u;
        __syncthreads();
        pi ^= 1;
    }
    int pre = sbuf[pi][tid] - c;
    if (tid <= BSZ2 && nlo + tid <= N) offs[nlo + tid] = base + pre;
    lcnt[tid] = pre;                                        // reuse as cursor
    __syncthreads();
    if (len <= CAP) {
        for (int i = tid; i < len; i += 256) {
            unsigned p = pairs[base + i];
            int pos = atomicAdd(&lcnt[p & 127u], 1);
            lcsr[pos] = (int)(p >> 8);
        }
        __syncthreads();
        for (int i = tid; i < len; i += 256) csr[base + i] = lcsr[i];
    } else {
        for (int i = tid; i < len; i += 256) {
            unsigned p = pairs[base + i];
            int pos = atomicAdd(&lcnt[p & 127u], 1);
            csr[base + pos] = (int)(p >> 8);
        }
    }
}

// --- gather-mean, column-HALF tasks with TRUE XCD affinity -----------------
// Task = (8-node group g, column half h). Block reads its actual XCD id
// (HW_REG_XCC_ID) and prefers h = xcc&1 via two atomic work queues; when
// the preferred queue is exhausted it falls back to the other (overflow
// only happens after a queue is fully drained, so every task is assigned
// exactly once). Each XCD then misses on only ONE 128B half (= one L2
// line) of each src row: per-XCD xb replication 22MB -> 12.8MB.
// 32-lane group per node: e = l>>3 edge slot (4 edges), fl = l&7 chunk.
__global__ __launch_bounds__(256) void gather_kernel(
    const int* __restrict__ offs, const int* __restrict__ csr,
    const unsigned short* __restrict__ xb, unsigned short* __restrict__ aggb,
    int* __restrict__ queue, int N, int NG) {
    __shared__ int stask;
    int tid = threadIdx.x;
    if (tid == 0) {
        unsigned xcc;
        asm("s_getreg_b32 %0, hwreg(HW_REG_XCC_ID)" : "=s"(xcc));
        int pref = (int)(xcc & 1u);
        int i = atomicAdd(&queue[pref], 1);
        int h = pref;
        if (i >= NG) {                      // preferred drained -> steal
            i = atomicAdd(&queue[1 - pref], 1);
            h = 1 - pref;
        }
        stask = min(i, NG - 1) * 2 + h;     // clamp is unreachable-safe
    }
    __syncthreads();
    int task = stask;
    int g    = task >> 1;
    int h    = task & 1;
    int l    = tid & 31;
    int e    = l >> 3;                 // edge slot 0..3
    int fl   = l & 7;                  // 16B chunk within the 128B half
    int cb   = h * 64 + fl * 8;        // short offset into row
    int n    = g * 8 + (tid >> 5);

    f32x2 acc[4];
#pragma unroll
    for (int j = 0; j < 4; ++j) {
        f32x2 z = {0.f, 0.f};
        acc[j] = z;
    }
    float inv = 0.f;
    if (n < N) {
        int beg = offs[n], end = offs[n + 1];
        int deg = end - beg;
        int k = beg;
        for (; k + 8 <= end; k += 8) {       // two full 4-edge slots
            int s0 = csr[k + e];
            int s1 = csr[k + 4 + e];
            uint4 v0 = *(const uint4*)(xb + (size_t)s0 * D128 + cb);
            uint4 v1 = *(const uint4*)(xb + (size_t)s1 * D128 + cb);
            acc[0] += bf2(v0.x); acc[1] += bf2(v0.y);
            acc[2] += bf2(v0.z); acc[3] += bf2(v0.w);
            acc[0] += bf2(v1.x); acc[1] += bf2(v1.y);
            acc[2] += bf2(v1.z); acc[3] += bf2(v1.w);
        }
        for (; k < end; k += 4) {            // masked tail slots
            int idx = k + e;
            bool ok = idx < end;
            int s = csr[ok ? idx : end - 1];
            uint4 v = *(const uint4*)(xb + (size_t)s * D128 + cb);
            if (ok) {
                acc[0] += bf2(v.x); acc[1] += bf2(v.y);
                acc[2] += bf2(v.z); acc[3] += bf2(v.w);
            }
        }
        if (deg > 0) inv = 1.0f / (float)deg;
    }
    float r[8];
#pragma unroll
    for (int j = 0; j < 4; ++j) {
        r[2 * j]     = acc[j].x;
        r[2 * j + 1] = acc[j].y;
    }
#pragma unroll
    for (int j = 0; j < 8; ++j) {            // reduce over e (lane bits 3,4)
        r[j] += __shfl_xor(r[j], 8, 64);
        r[j] += __shfl_xor(r[j], 16, 64);
    }
    if (e == 0 && n < N) {                   // 8 lanes write the 128B half
        uint4 o;
        o.x = (unsigned)f2bf(r[0] * inv) | ((unsigned)f2bf(r[1] * inv) << 16);
        o.y = (unsigned)f2bf(r[2] * inv) | ((unsigned)f2bf(r[3] * inv) << 16);
        o.z = (unsigned)f2bf(r[4] * inv) | ((unsigned)f2bf(r[5] * inv) << 16);
        o.w = (unsigned)f2bf(r[6] * inv) | ((unsigned)f2bf(r[7] * inv) << 16);
        *(uint4*)(aggb + (size_t)n * D128 + cb) = o;
    } else if (e == 0) {                     // padded rows: zero fill
        uint4 z = make_uint4(0, 0, 0, 0);
        *(uint4*)(aggb + (size_t)n * D128 + cb) = z;
    }
}

// --- MFMA dual GEMM -> bf16 h + BN stats into replicated accumulators ------
// K=256: ksteps 0-3 read aggb, 4-7 read xb. No b_l (cancelled by BN).
__global__ __launch_bounds__(256) void mfma_kernel(
    const unsigned short* __restrict__ aggb, const unsigned short* __restrict__ xb,
    const unsigned short* __restrict__ Bsw,
    unsigned short* __restrict__ h16, float* __restrict__ stats, int N) {
    __shared__ float red[4][256];
    int tid  = threadIdx.x;
    int w    = tid >> 6;
    int lane = tid & 63;
    int lc   = lane & 15;    // tile col
    int lq   = lane >> 4;    // quarter
    int rowBase = blockIdx.x * 128 + w * 32;

    f32x4 acc[2][8];
#pragma unroll
    for (int c = 0; c < 8; ++c) {
        f32x4 z = {0.f, 0.f, 0.f, 0.f};
        acc[0][c] = z;
        acc[1][c] = z;
    }
    int r0  = rowBase + lc;
    int r1  = rowBase + 16 + lc;
    int r0c = min(r0, N - 1);
    int r1c = min(r1, N - 1);
    for (int t = 0; t < 8; ++t) {
        const unsigned short* p0;
        const unsigned short* p1;
        if (t < 4) {
            int off = t * 32 + lq * 8;
            p0 = aggb + (size_t)r0 * D128 + off;
            p1 = aggb + (size_t)r1 * D128 + off;
        } else {
            int off = (t - 4) * 32 + lq * 8;
            p0 = xb + (size_t)r0c * D128 + off;
            p1 = xb + (size_t)r1c * D128 + off;
        }
        bf16x8 a0 = *(const bf16x8*)p0;
        bf16x8 a1 = *(const bf16x8*)p1;
#pragma unroll
        for (int c = 0; c < 8; ++c) {
            bf16x8 bf = *(const bf16x8*)(Bsw + ((size_t)((t * 8 + c) * 64 + lane)) * 8);
            acc[0][c] = __builtin_amdgcn_mfma_f32_16x16x32_bf16(a0, bf, acc[0][c], 0, 0, 0);
            acc[1][c] = __builtin_amdgcn_mfma_f32_16x16x32_bf16(a1, bf, acc[1][c], 0, 0, 0);
        }
    }
    float s[8], ss[8];
#pragma unroll
    for (int c = 0; c < 8; ++c) { s[c] = 0.f; ss[c] = 0.f; }
#pragma unroll
    for (int rh = 0; rh < 2; ++rh) {
#pragma unroll
        for (int reg = 0; reg < 4; ++reg) {
            int row = rowBase + rh * 16 + lq * 4 + reg;   // C-layout row
            if (row < N) {
#pragma unroll
                for (int c = 0; c < 8; ++c) {
                    float v = acc[rh][c][reg];
                    h16[(size_t)row * D128 + c * 16 + lc] = f2bf(v);
                    s[c]  += v;
                    ss[c] += v * v;
                }
            }
        }
    }
#pragma unroll
    for (int c = 0; c < 8; ++c) {
        s[c]  += __shfl_xor(s[c], 16, 64);
        s[c]  += __shfl_xor(s[c], 32, 64);
        ss[c] += __shfl_xor(ss[c], 16, 64);
        ss[c] += __shfl_xor(ss[c], 32, 64);
    }
    if (lq == 0) {
#pragma unroll
        for (int c = 0; c < 8; ++c) {
            red[w][c * 16 + lc]       = s[c];
            red[w][128 + c * 16 + lc] = ss[c];
        }
    }
    __syncthreads();
    float tot = red[0][tid] + red[1][tid] + red[2][tid] + red[3][tid];
    atomicAdd(&stats[(blockIdx.x & (SREP - 1)) * 256 + tid], tot);
}

// --- finalize: sum stat replicas, BN params in LDS, out = relu(...) --------
__global__ __launch_bounds__(256) void finalize_kernel(
    const unsigned short* __restrict__ h16, const unsigned short* __restrict__ xb,
    const float* __restrict__ stats, const float* __restrict__ gamma,
    const float* __restrict__ beta, float* __restrict__ out,
    long long total4, float invN) {
    __shared__ float sscl[D128];
    __shared__ float sshf[D128];
    int tid = threadIdx.x;
    if (tid < D128) {
        float sum = 0.f, sq = 0.f;
#pragma unroll
        for (int r = 0; r < SREP; ++r) {
            sum += stats[r * 256 + tid];
            sq  += stats[r * 256 + 128 + tid];
        }
        float mean = sum * invN;
        float var  = sq * invN - mean * mean;
        float istd = rsqrtf(var + 1e-5f);
        float sc   = gamma[tid] * istd;
        sscl[tid] = sc;
        sshf[tid] = beta[tid] - mean * sc;
    }
    __syncthreads();
    long long i = (long long)blockIdx.x * 256 + tid;
    if (i >= total4) return;
    int d = (int)((i * 4) & 127);
    uint2 hv = ((const uint2*)h16)[i];
    uint2 xv = ((const uint2*)xb)[i];
    float4 o;
    o.x = fmaxf(fmaf(bflo(hv.x), sscl[d],     sshf[d])     + bflo(xv.x), 0.f);
    o.y = fmaxf(fmaf(bfhi(hv.x), sscl[d + 1], sshf[d + 1]) + bfhi(xv.x), 0.f);
    o.z = fmaxf(fmaf(bflo(hv.y), sscl[d + 2], sshf[d + 2]) + bflo(xv.y), 0.f);
    o.w = fmaxf(fmaf(bfhi(hv.y), sscl[d + 3], sshf[d + 3]) + bfhi(xv.y), 0.f);
    ((float4*)out)[i] = o;
}

extern "C" void kernel_launch(void* const* d_in, const int* in_sizes, int n_in,
                              void* d_out, int out_size, void* d_ws, size_t ws_size,
                              hipStream_t stream) {
    const float* x     = (const float*)d_in[0];
    const int*   eidx  = (const int*)d_in[1];
    const float* W_l   = (const float*)d_in[2];
    const float* W_r   = (const float*)d_in[4];
    const float* gamma = (const float*)d_in[5];
    const float* beta  = (const float*)d_in[6];

    const int D = in_sizes[3];            // 128
    const int N = in_sizes[0] / D;        // 100000
    const int E = in_sizes[1] / 2;        // 1600000

    const int* src = eidx;
    const int* dst = eidx + E;

    const int NBLK  = (N + 127) / 128;        // mfma blocks (782)
    const int Npad  = NBLK * 128;             // padded rows (100096)
    const int NG    = Npad / 8;               // gather node-groups (12512)
    const int NBUK  = (N + BSZ2 - 1) / BSZ2;  // buckets (782)
    const int M     = NBUK * SBLK;            // ghist cells (200192)
    const int NB2   = (M + 1023) / 1024;      // ghist-scan blocks (196, <=256)
    const int chunk = (E + SBLK - 1) / SBLK;  // edges per sort block (6250)
    const int total4 = N * D128 / 4;          // float4s in x

    // workspace layout (byte cursor, 64B-aligned chunks)
    char* wp = (char*)d_ws;
    auto alloc = [&](size_t bytes) {
        char* p = wp;
        wp += (bytes + 63) & ~(size_t)63;
        return p;
    };
    float*    stats = (float*)   alloc((size_t)SREP * 256 * 4);
    int*      queue = (int*)     alloc(64);
    int*      offs  = (int*)     alloc((size_t)(N + 1) * 4);
    int*      csr   = (int*)     alloc((size_t)E * 4);
    unsigned* pairs = (unsigned*)alloc((size_t)E * 4);
    int*      ghist = (int*)     alloc((size_t)M * 4);
    int*      gsc   = (int*)     alloc((size_t)(M + 1) * 4);
    int*      bsum  = (int*)     alloc(1024 * 4);
    unsigned short* Bsw  = (unsigned short*)alloc(4096 * 16);
    unsigned short* xb   = (unsigned short*)alloc((size_t)N * D128 * 2);
    unsigned short* aggb = (unsigned short*)alloc((size_t)Npad * D128 * 2);
    unsigned short* h16  = (unsigned short*)alloc((size_t)N * D128 * 2);

    float* outp = (float*)d_out;
    float invN = 1.0f / (float)N;

    // bucket hist (+ fused x->bf16 + prep + queue reset) -> scan -> scatter
    bhist_kernel<<<SBLK, 256, 0, stream>>>(dst, ghist, x, xb, W_l, W_r, Bsw,
                                           stats, queue, E, chunk, NBUK, total4);
    partial_kernel<<<NB2, 256, 0, stream>>>(ghist, bsum, M);
    scan_final_kernel<<<NB2, 256, 0, stream>>>(ghist, bsum, gsc, M, NB2);
    bscatter_kernel<<<SBLK, 256, 0, stream>>>(src, dst, gsc, pairs, E, chunk, NBUK);

    // per-bucket CSR build (also writes offs)
    csrbuild_kernel<<<NBUK, 256, 0, stream>>>(pairs, gsc, csr, offs, N, NBUK, E);

    // column-half gather with true XCD affinity: 2 tasks per node-group
    gather_kernel<<<NG * 2, 256, 0, stream>>>(offs, csr, xb, aggb, queue, N, NG);

    mfma_kernel<<<NBLK, 256, 0, stream>>>(aggb, xb, Bsw, h16, stats, N);

    {
        long long t4 = (long long)N * D128 / 4;
        finalize_kernel<<<(int)((t4 + 255) / 256), 256, 0, stream>>>(
            h16, xb, stats, gamma, beta, outp, t4, invN);
    }
}

// Round 5
// 300.304 us; speedup vs baseline: 1.8189x; 1.8189x over previous
//
#include <hip/hip_runtime.h>
#include <hip/hip_bf16.h>

// ---------------------------------------------------------------------------
// ResidualSAGEBlock: block-private bucket sort -> CSR(+offs) -> bf16 gather ->
// MFMA bf16 dual GEMM (+in-kernel BN stats) -> finalize(BN+res+ReLU).
// N=100000, D=128, E=1600000.
// R2: CSR gather replaced float-atomic scatter: 3095->812us.
// R7: 3-pass block-private counting sort: 757->409us.
// R8: bf16 gather source; offs folded into csrbuild; packed pairs: 409->306us.
// R10: bf16 h; bf16 residual; bnparam folded into finalize: 306->303us.
// R11: 12->9 dispatches; in-mfma stat atomics: 303->296us.
// R12: 32-way replicated stats: 296->290us.
// R13 FAILED: gather fused into mfma: 782-block grid underfills (occ 19%,
//      fetch 3.6->1.6TB/s): 290->316us. Reverted.
// R14 NEUTRAL: pk-f32 accumulate, buckets 128, prep merged: 291.9us.
//      Gather NOT VALU-limited; time == FETCH(177MB) / 3.2TB/s.
// R15 FAILED: column-quarter w/ ASSUMED blockIdx%8->XCD map: FETCH 304MB.
// R16 FAILED: HW_REG_XCC_ID + work queues: FETCH 350MB (= no-affinity
//      model) AND rate 1.26TB/s (halved MLP, doubled csr walks): 546us.
//      CONCLUSION: gather floor = 177MB @ ~3.5TB/s ~= 57us. Front closed.
// R17: revert to R14; merge partial+scan_final into one kernel via
//      published partials + flag spin (196 blocks <= CU count, serial
//      stream -> co-residency guaranteed; device-scope flags for cross-XCD
//      visibility). -1 launch, -1 ghist pass.
// ---------------------------------------------------------------------------

#define D128 128
#define BSH2 7          // log2(nodes per bucket)
#define BSZ2 128        // nodes per bucket
#define MAXBUK 1024     // LDS bound for buckets (NBUK=782 actual)
#define SBLK 256        // sort blocks
#define CAP  2816       // csrbuild LDS capacity (mean 2048, +17 sigma)
#define SREP 32         // stat replicas

typedef short bf16x8 __attribute__((ext_vector_type(8)));
typedef float f32x4  __attribute__((ext_vector_type(4)));
typedef float f32x2  __attribute__((ext_vector_type(2)));

static __device__ __forceinline__ unsigned short f2bf(float f) {
    unsigned u = __builtin_bit_cast(unsigned, f);
    unsigned r = u + 0x7fffu + ((u >> 16) & 1u);   // round-to-nearest-even
    return (unsigned short)(r >> 16);
}
static __device__ __forceinline__ float bflo(unsigned u) {   // low bf16 -> f32
    return __builtin_bit_cast(float, u << 16);
}
static __device__ __forceinline__ float bfhi(unsigned u) {   // high bf16 -> f32
    return __builtin_bit_cast(float, u & 0xffff0000u);
}
static __device__ __forceinline__ f32x2 bf2(unsigned u) {    // {lo,hi} pair
    f32x2 r;
    r.x = bflo(u);
    r.y = bfhi(u);
    return r;
}

// --- sort pass 1: per-block bucket histogram + fused x->bf16 conversion ----
// Blocks 0..15 additionally build swizzled bf16 B for MFMA and zero the
// replicated stats; block 16 zeroes the scan flags.
//   Bsw[t][c][lane][j] = Wcat[t*32 + (lane>>4)*8 + j][c*16 + (lane&15)]
//   Wcat[k][d] = k<128 ? Wl[d][k] : Wr[d][k-128].
__global__ __launch_bounds__(256) void bhist_kernel(
    const int* __restrict__ dst, int* __restrict__ ghist,
    const float* __restrict__ x, unsigned short* __restrict__ xb,
    const float* __restrict__ Wl, const float* __restrict__ Wr,
    unsigned short* __restrict__ Bsw, float* __restrict__ stats,
    int* __restrict__ flags,
    int E, int chunk, int NBUK, int total4) {
    __shared__ int lh[MAXBUK];
    int tid = threadIdx.x;
    int b   = blockIdx.x;
    if (b < 16) {                       // merged prep work
        int idx = b * 256 + tid;        // 0..4095
        stats[idx] = 0.f;               // 2 x 4096 = SREP*256 floats
        stats[idx + 4096] = 0.f;
        int l = idx & 63;
        int c = (idx >> 6) & 7;
        int t = idx >> 9;
        int d = c * 16 + (l & 15);
        int kbase = t * 32 + (l >> 4) * 8;
        unsigned short o[8];
#pragma unroll
        for (int j = 0; j < 8; ++j) {
            int k = kbase + j;
            float v = (k < 128) ? Wl[d * 128 + k] : Wr[d * 128 + (k - 128)];
            o[j] = f2bf(v);
        }
        *(uint4*)(Bsw + (size_t)idx * 8) = *(const uint4*)o;
    } else if (b == 16) {
        flags[tid] = 0;                 // scan flags (NB2<=256)
    }
    for (int i = tid; i < NBUK; i += 256) lh[i] = 0;
    __syncthreads();
    int beg = b * chunk;
    int end = min(beg + chunk, E);
    for (int i = beg + tid; i < end; i += 256)
        atomicAdd(&lh[dst[i] >> BSH2], 1);
    __syncthreads();
    for (int i = tid; i < NBUK; i += 256) ghist[i * SBLK + b] = lh[i];
    // fused streaming conversion x (fp32) -> xb (bf16)
    for (int i = b * 256 + tid; i < total4; i += 256 * SBLK) {
        float4 v = ((const float4*)x)[i];
        uint2 o;
        o.x = (unsigned)f2bf(v.x) | ((unsigned)f2bf(v.y) << 16);
        o.y = (unsigned)f2bf(v.z) | ((unsigned)f2bf(v.w) << 16);
        ((uint2*)xb)[i] = o;
    }
}

// --- single-pass scan: per-block partial -> publish(flag) -> spin -> scan --
// NB2 (196) <= CU count and the stream is serial, so every block is
// co-resident; device-scope flag atomics give cross-XCD visibility.
__global__ __launch_bounds__(256) void scan_kernel(
    const int* __restrict__ deg, int* __restrict__ partials,
    int* __restrict__ flags, int* __restrict__ offs, int M, int NB2) {
    __shared__ int sb[2][256];
    int tid = threadIdx.x;
    int b   = blockIdx.x;

    int base = b * 1024 + tid * 4;
    int d0 = 0, d1 = 0, d2 = 0, d3 = 0;
    if (base + 3 < M) {
        int4 v = *(const int4*)(deg + base);
        d0 = v.x; d1 = v.y; d2 = v.z; d3 = v.w;
    } else {
        if (base     < M) d0 = deg[base];
        if (base + 1 < M) d1 = deg[base + 1];
        if (base + 2 < M) d2 = deg[base + 2];
        if (base + 3 < M) d3 = deg[base + 3];
    }
    int s = d0 + d1 + d2 + d3;

    // block partial sum
    sb[0][tid] = s;
    __syncthreads();
    for (int off = 128; off > 0; off >>= 1) {
        if (tid < off) sb[0][tid] += sb[0][tid + off];
        __syncthreads();
    }
    if (tid == 0) {
        partials[b] = sb[0][0];
        __threadfence();
        atomicExch(&flags[b], 1);
    }
    // wait for all partials
    for (int i = tid; i < NB2; i += 256)
        while (atomicAdd(&flags[i], 0) == 0) { }
    __syncthreads();

    // scan partials (exclusive up to this block)
    int bv = (tid < NB2) ? partials[tid] : 0;
    sb[0][tid] = bv;
    __syncthreads();
    int bpi = 0;
    for (int off = 1; off < 256; off <<= 1) {
        int u = sb[bpi][tid];
        if (tid >= off) u += sb[bpi][tid - off];
        sb[bpi ^ 1][tid] = u;
        __syncthreads();
        bpi ^= 1;
    }
    int ebsum = (b > 0) ? sb[bpi][b - 1] : 0;
    __syncthreads();

    // intra-block scan of the 4-wide sums
    sb[0][tid] = s;
    __syncthreads();
    int pi = 0;
    for (int off = 1; off < 256; off <<= 1) {
        int u = sb[pi][tid];
        if (tid >= off) u += sb[pi][tid - off];
        sb[pi ^ 1][tid] = u;
        __syncthreads();
        pi ^= 1;
    }
    int pre = sb[pi][tid] - s + ebsum;
    if (base + 3 < M) {
        int4 o = make_int4(pre, pre + d0, pre + d0 + d1, pre + d0 + d1 + d2);
        *(int4*)(offs + base) = o;
    } else {
        int p = pre;
        if (base     < M) { offs[base]     = p; p += d0; }
        if (base + 1 < M) { offs[base + 1] = p; p += d1; }
        if (base + 2 < M) { offs[base + 2] = p; }
    }
}

// --- sort pass 2: scatter packed (src<<8 | dst&255) into private ranges ----
__global__ __launch_bounds__(256) void bscatter_kernel(
    const int* __restrict__ src, const int* __restrict__ dst,
    const int* __restrict__ gsc, unsigned* __restrict__ pairs,
    int E, int chunk, int NBUK) {
    __shared__ int lcur[MAXBUK];
    int tid = threadIdx.x;
    int b   = blockIdx.x;
    for (int i = tid; i < NBUK; i += 256) lcur[i] = gsc[i * SBLK + b];
    __syncthreads();
    int beg = b * chunk;
    int end = min(beg + chunk, E);
    for (int i = beg + tid; i < end; i += 256) {
        int d = dst[i];
        int s = src[i];
        int pos = atomicAdd(&lcur[d >> BSH2], 1);
        pairs[pos] = ((unsigned)s << 8) | (unsigned)(d & 255);
    }
}

// --- per-bucket: local node histogram + scan -> offs; LDS sort -> csr ------
// BSZ2=128: counters 128..255 stay zero; 256-wide scan still yields correct
// exclusive prefixes, and pre[128] == len covers the offs[bucket_end] write.
__global__ __launch_bounds__(256) void csrbuild_kernel(
    const unsigned* __restrict__ pairs, const int* __restrict__ gsc,
    int* __restrict__ csr, int* __restrict__ offs, int N, int NBUK, int E) {
    __shared__ int lcnt[256];
    __shared__ int sbuf[2][256];
    __shared__ int lcsr[CAP];
    int b   = blockIdx.x;
    int tid = threadIdx.x;
    int nlo = b << BSH2;
    int base = gsc[(size_t)b * SBLK];                       // bucket start
    int end  = (b + 1 < NBUK) ? gsc[(size_t)(b + 1) * SBLK] : E;
    int len  = end - base;
    lcnt[tid] = 0;
    __syncthreads();
    for (int i = tid; i < len; i += 256)
        atomicAdd(&lcnt[pairs[base + i] & 127u], 1);
    __syncthreads();
    int c = lcnt[tid];
    sbuf[0][tid] = c;
    __syncthreads();
    int pi = 0;
    for (int off = 1; off < 256; off <<= 1) {
        int u = sbuf[pi][tid];
        if (tid >= off) u += sbuf[pi][tid - off];
        sbuf[pi ^ 1][tid] = u;
        __syncthreads();
        pi ^= 1;
    }
    int pre = sbuf[pi][tid] - c;
    if (tid <= BSZ2 && nlo + tid <= N) offs[nlo + tid] = base + pre;
    lcnt[tid] = pre;                                        // reuse as cursor
    __syncthreads();
    if (len <= CAP) {
        for (int i = tid; i < len; i += 256) {
            unsigned p = pairs[base + i];
            int pos = atomicAdd(&lcnt[p & 127u], 1);
            lcsr[pos] = (int)(p >> 8);
        }
        __syncthreads();
        for (int i = tid; i < len; i += 256) csr[base + i] = lcsr[i];
    } else {
        for (int i = tid; i < len; i += 256) {
            unsigned p = pairs[base + i];
            int pos = atomicAdd(&lcnt[p & 127u], 1);
            csr[base + pos] = (int)(p >> 8);
        }
    }
}

// --- gather-mean from bf16 xb: aggb[n][:] = mean of xb[src] rows -----------
// Accumulates as float2 so the compiler can emit v_pk_add_f32.
__global__ __launch_bounds__(256) void gather_kernel(
    const int* __restrict__ offs, const int* __restrict__ csr,
    const unsigned short* __restrict__ xb, unsigned short* __restrict__ aggb,
    int N, int Npad) {
    int tid  = threadIdx.x;
    int l    = tid & 31;
    int half = l >> 4;
    int fl   = l & 15;
    int n    = blockIdx.x * 8 + (tid >> 5);
    if (n >= Npad) return;
    f32x2 f[4], g[4];
#pragma unroll
    for (int j = 0; j < 4; ++j) {
        f32x2 z = {0.f, 0.f};
        f[j] = z;
        g[j] = z;
    }
    float inv = 0.f;
    if (n < N) {
        int beg = offs[n], end = offs[n + 1];
        int deg = end - beg;
        int k = beg;
        for (; k + 8 <= end; k += 8) {
            int s0 = csr[k + half];
            int s1 = csr[k + 2 + half];
            int s2 = csr[k + 4 + half];
            int s3 = csr[k + 6 + half];
            uint4 v0 = *(const uint4*)(xb + (size_t)s0 * D128 + fl * 8);
            uint4 v1 = *(const uint4*)(xb + (size_t)s1 * D128 + fl * 8);
            uint4 v2 = *(const uint4*)(xb + (size_t)s2 * D128 + fl * 8);
            uint4 v3 = *(const uint4*)(xb + (size_t)s3 * D128 + fl * 8);
            f[0] += bf2(v0.x); f[1] += bf2(v0.y);
            f[2] += bf2(v0.z); f[3] += bf2(v0.w);
            g[0] += bf2(v1.x); g[1] += bf2(v1.y);
            g[2] += bf2(v1.z); g[3] += bf2(v1.w);
            f[0] += bf2(v2.x); f[1] += bf2(v2.y);
            f[2] += bf2(v2.z); f[3] += bf2(v2.w);
            g[0] += bf2(v3.x); g[1] += bf2(v3.y);
            g[2] += bf2(v3.z); g[3] += bf2(v3.w);
        }
        if (end - k >= 4) {
            int s0 = csr[k + half];
            int s1 = csr[k + 2 + half];
            uint4 v0 = *(const uint4*)(xb + (size_t)s0 * D128 + fl * 8);
            uint4 v1 = *(const uint4*)(xb + (size_t)s1 * D128 + fl * 8);
            f[0] += bf2(v0.x); f[1] += bf2(v0.y);
            f[2] += bf2(v0.z); f[3] += bf2(v0.w);
            g[0] += bf2(v1.x); g[1] += bf2(v1.y);
            g[2] += bf2(v1.z); g[3] += bf2(v1.w);
            k += 4;
        }
        if (end - k >= 2) {
            int s0 = csr[k + half];
            uint4 v0 = *(const uint4*)(xb + (size_t)s0 * D128 + fl * 8);
            f[0] += bf2(v0.x); f[1] += bf2(v0.y);
            f[2] += bf2(v0.z); f[3] += bf2(v0.w);
            k += 2;
        }
        if (k < end && half == 0) {
            int s0 = csr[k];
            uint4 v0 = *(const uint4*)(xb + (size_t)s0 * D128 + fl * 8);
            f[0] += bf2(v0.x); f[1] += bf2(v0.y);
            f[2] += bf2(v0.z); f[3] += bf2(v0.w);
        }
        if (deg > 0) inv = 1.0f / (float)deg;
    }
    float r[8];
#pragma unroll
    for (int j = 0; j < 4; ++j) {
        f[j] += g[j];
        r[2 * j]     = f[j].x;
        r[2 * j + 1] = f[j].y;
    }
#pragma unroll
    for (int j = 0; j < 8; ++j)
        r[j] += __shfl_xor(r[j], 16, 64);   // combine halves (stays in group)
    if (half == 0) {
        uint4 o;
        o.x = (unsigned)f2bf(r[0] * inv) | ((unsigned)f2bf(r[1] * inv) << 16);
        o.y = (unsigned)f2bf(r[2] * inv) | ((unsigned)f2bf(r[3] * inv) << 16);
        o.z = (unsigned)f2bf(r[4] * inv) | ((unsigned)f2bf(r[5] * inv) << 16);
        o.w = (unsigned)f2bf(r[6] * inv) | ((unsigned)f2bf(r[7] * inv) << 16);
        *(uint4*)(aggb + (size_t)n * D128 + fl * 8) = o;
    }
}

// --- MFMA dual GEMM -> bf16 h + BN stats into replicated accumulators ------
// K=256: ksteps 0-3 read aggb, 4-7 read xb. No b_l (cancelled by BN).
__global__ __launch_bounds__(256) void mfma_kernel(
    const unsigned short* __restrict__ aggb, const unsigned short* __restrict__ xb,
    const unsigned short* __restrict__ Bsw,
    unsigned short* __restrict__ h16, float* __restrict__ stats, int N) {
    __shared__ float red[4][256];
    int tid  = threadIdx.x;
    int w    = tid >> 6;
    int lane = tid & 63;
    int lc   = lane & 15;    // tile col
    int lq   = lane >> 4;    // quarter
    int rowBase = blockIdx.x * 128 + w * 32;

    f32x4 acc[2][8];
#pragma unroll
    for (int c = 0; c < 8; ++c) {
        f32x4 z = {0.f, 0.f, 0.f, 0.f};
        acc[0][c] = z;
        acc[1][c] = z;
    }
    int r0  = rowBase + lc;
    int r1  = rowBase + 16 + lc;
    int r0c = min(r0, N - 1);
    int r1c = min(r1, N - 1);
    for (int t = 0; t < 8; ++t) {
        const unsigned short* p0;
        const unsigned short* p1;
        if (t < 4) {
            int off = t * 32 + lq * 8;
            p0 = aggb + (size_t)r0 * D128 + off;
            p1 = aggb + (size_t)r1 * D128 + off;
        } else {
            int off = (t - 4) * 32 + lq * 8;
            p0 = xb + (size_t)r0c * D128 + off;
            p1 = xb + (size_t)r1c * D128 + off;
        }
        bf16x8 a0 = *(const bf16x8*)p0;
        bf16x8 a1 = *(const bf16x8*)p1;
#pragma unroll
        for (int c = 0; c < 8; ++c) {
            bf16x8 bf = *(const bf16x8*)(Bsw + ((size_t)((t * 8 + c) * 64 + lane)) * 8);
            acc[0][c] = __builtin_amdgcn_mfma_f32_16x16x32_bf16(a0, bf, acc[0][c], 0, 0, 0);
            acc[1][c] = __builtin_amdgcn_mfma_f32_16x16x32_bf16(a1, bf, acc[1][c], 0, 0, 0);
        }
    }
    float s[8], ss[8];
#pragma unroll
    for (int c = 0; c < 8; ++c) { s[c] = 0.f; ss[c] = 0.f; }
#pragma unroll
    for (int rh = 0; rh < 2; ++rh) {
#pragma unroll
        for (int reg = 0; reg < 4; ++reg) {
            int row = rowBase + rh * 16 + lq * 4 + reg;   // C-layout row
            if (row < N) {
#pragma unroll
                for (int c = 0; c < 8; ++c) {
                    float v = acc[rh][c][reg];
                    h16[(size_t)row * D128 + c * 16 + lc] = f2bf(v);
                    s[c]  += v;
                    ss[c] += v * v;
                }
            }
        }
    }
#pragma unroll
    for (int c = 0; c < 8; ++c) {
        s[c]  += __shfl_xor(s[c], 16, 64);
        s[c]  += __shfl_xor(s[c], 32, 64);
        ss[c] += __shfl_xor(ss[c], 16, 64);
        ss[c] += __shfl_xor(ss[c], 32, 64);
    }
    if (lq == 0) {
#pragma unroll
        for (int c = 0; c < 8; ++c) {
            red[w][c * 16 + lc]       = s[c];
            red[w][128 + c * 16 + lc] = ss[c];
        }
    }
    __syncthreads();
    float tot = red[0][tid] + red[1][tid] + red[2][tid] + red[3][tid];
    atomicAdd(&stats[(blockIdx.x & (SREP - 1)) * 256 + tid], tot);
}

// --- finalize: sum stat replicas, BN params in LDS, out = relu(...) --------
__global__ __launch_bounds__(256) void finalize_kernel(
    const unsigned short* __restrict__ h16, const unsigned short* __restrict__ xb,
    const float* __restrict__ stats, const float* __restrict__ gamma,
    const float* __restrict__ beta, float* __restrict__ out,
    long long total4, float invN) {
    __shared__ float sscl[D128];
    __shared__ float sshf[D128];
    int tid = threadIdx.x;
    if (tid < D128) {
        float sum = 0.f, sq = 0.f;
#pragma unroll
        for (int r = 0; r < SREP; ++r) {
            sum += stats[r * 256 + tid];
            sq  += stats[r * 256 + 128 + tid];
        }
        float mean = sum * invN;
        float var  = sq * invN - mean * mean;
        float istd = rsqrtf(var + 1e-5f);
        float sc   = gamma[tid] * istd;
        sscl[tid] = sc;
        sshf[tid] = beta[tid] - mean * sc;
    }
    __syncthreads();
    long long i = (long long)blockIdx.x * 256 + tid;
    if (i >= total4) return;
    int d = (int)((i * 4) & 127);
    uint2 hv = ((const uint2*)h16)[i];
    uint2 xv = ((const uint2*)xb)[i];
    float4 o;
    o.x = fmaxf(fmaf(bflo(hv.x), sscl[d],     sshf[d])     + bflo(xv.x), 0.f);
    o.y = fmaxf(fmaf(bfhi(hv.x), sscl[d + 1], sshf[d + 1]) + bfhi(xv.x), 0.f);
    o.z = fmaxf(fmaf(bflo(hv.y), sscl[d + 2], sshf[d + 2]) + bflo(xv.y), 0.f);
    o.w = fmaxf(fmaf(bfhi(hv.y), sscl[d + 3], sshf[d + 3]) + bfhi(xv.y), 0.f);
    ((float4*)out)[i] = o;
}

extern "C" void kernel_launch(void* const* d_in, const int* in_sizes, int n_in,
                              void* d_out, int out_size, void* d_ws, size_t ws_size,
                              hipStream_t stream) {
    const float* x     = (const float*)d_in[0];
    const int*   eidx  = (const int*)d_in[1];
    const float* W_l   = (const float*)d_in[2];
    const float* W_r   = (const float*)d_in[4];
    const float* gamma = (const float*)d_in[5];
    const float* beta  = (const float*)d_in[6];

    const int D = in_sizes[3];            // 128
    const int N = in_sizes[0] / D;        // 100000
    const int E = in_sizes[1] / 2;        // 1600000

    const int* src = eidx;
    const int* dst = eidx + E;

    const int NBLK  = (N + 127) / 128;        // mfma blocks (782)
    const int Npad  = NBLK * 128;             // padded rows (100096)
    const int NBUK  = (N + BSZ2 - 1) / BSZ2;  // buckets (782)
    const int M     = NBUK * SBLK;            // ghist cells (200192)
    const int NB2   = (M + 1023) / 1024;      // scan blocks (196, <=256)
    const int chunk = (E + SBLK - 1) / SBLK;  // edges per sort block (6250)
    const int total4 = N * D128 / 4;          // float4s in x

    // workspace layout (byte cursor, 64B-aligned chunks)
    char* wp = (char*)d_ws;
    auto alloc = [&](size_t bytes) {
        char* p = wp;
        wp += (bytes + 63) & ~(size_t)63;
        return p;
    };
    float*    stats = (float*)   alloc((size_t)SREP * 256 * 4);
    int*      flags = (int*)     alloc(256 * 4);
    int*      offs  = (int*)     alloc((size_t)(N + 1) * 4);
    int*      csr   = (int*)     alloc((size_t)E * 4);
    unsigned* pairs = (unsigned*)alloc((size_t)E * 4);
    int*      ghist = (int*)     alloc((size_t)M * 4);
    int*      gsc   = (int*)     alloc((size_t)(M + 1) * 4);
    int*      bsum  = (int*)     alloc(1024 * 4);
    unsigned short* Bsw  = (unsigned short*)alloc(4096 * 16);
    unsigned short* xb   = (unsigned short*)alloc((size_t)N * D128 * 2);
    unsigned short* aggb = (unsigned short*)alloc((size_t)Npad * D128 * 2);
    unsigned short* h16  = (unsigned short*)alloc((size_t)N * D128 * 2);

    float* outp = (float*)d_out;
    float invN = 1.0f / (float)N;

    // bucket hist (+ fused x->bf16 + prep + flag reset) -> scan -> scatter
    bhist_kernel<<<SBLK, 256, 0, stream>>>(dst, ghist, x, xb, W_l, W_r, Bsw,
                                           stats, flags, E, chunk, NBUK, total4);
    scan_kernel<<<NB2, 256, 0, stream>>>(ghist, bsum, flags, gsc, M, NB2);
    bscatter_kernel<<<SBLK, 256, 0, stream>>>(src, dst, gsc, pairs, E, chunk, NBUK);

    // per-bucket CSR build (also writes offs)
    csrbuild_kernel<<<NBUK, 256, 0, stream>>>(pairs, gsc, csr, offs, N, NBUK, E);

    gather_kernel<<<Npad / 8, 256, 0, stream>>>(offs, csr, xb, aggb, N, Npad);

    mfma_kernel<<<NBLK, 256, 0, stream>>>(aggb, xb, Bsw, h16, stats, N);

    {
        long long t4 = (long long)N * D128 / 4;
        finalize_kernel<<<(int)((t4 + 255) / 256), 256, 0, stream>>>(
            h16, xb, stats, gamma, beta, outp, t4, invN);
    }
}

// Round 6
// 289.614 us; speedup vs baseline: 1.8861x; 1.0369x over previous
//
#include <hip/hip_runtime.h>
#include <hip/hip_bf16.h>

// ---------------------------------------------------------------------------
// ResidualSAGEBlock: block-private bucket sort -> CSR(+offs) -> bf16 gather ->
// MFMA bf16 dual GEMM (+in-kernel BN stats) -> finalize(BN+res+ReLU).
// N=100000, D=128, E=1600000.
// R2: CSR gather replaced float-atomic scatter: 3095->812us.
// R7: 3-pass block-private counting sort: 757->409us.
// R8: bf16 gather source; offs folded into csrbuild; packed pairs: 409->306us.
// R10: bf16 h; bf16 residual; bnparam folded into finalize: 306->303us.
// R11: 12->9 dispatches; in-mfma stat atomics: 303->296us.
// R12: 32-way replicated stats: 296->290us.
// R13 FAILED: gather fused into mfma: 782-block grid underfills (occ 19%):
//      290->316us. Reverted.
// R14 NEUTRAL: pk-f32 accumulate, buckets 128, prep merged: 291.9us.
//      Gather NOT VALU-limited; time == FETCH(177MB) / 3.5TB/s.
// R15 FAILED: column-quarter w/ ASSUMED blockIdx%8->XCD map: FETCH 304MB.
// R16 FAILED: HW_REG_XCC_ID + work queues: FETCH 350MB, rate 1.26TB/s.
//      Gather floor = 177MB @ ~3.5TB/s ~= 57us. Front closed.
// R17 FAILED: spin-flag merged scan: 256 threads x 196 flags device-scope
//      polling = cross-XCD atomic storm: 291.9->300.3us. Reverted.
// R18: sort-side occupancy. bhist/bscatter were 1 block/CU (1 wave/SIMD,
//      every load stall exposed). SBLK 256->512 (2 blk/CU, chunk 3125);
//      scan_final generalized to NB2<=1024 via 4-partials-per-thread
//      serial sum + LDS scan.
// ---------------------------------------------------------------------------

#define D128 128
#define BSH2 7          // log2(nodes per bucket)
#define BSZ2 128        // nodes per bucket
#define MAXBUK 1024     // LDS bound for buckets (NBUK=782 actual)
#define SBLK 512        // sort blocks (2 per CU)
#define CAP  2816       // csrbuild LDS capacity (mean 2046, +17 sigma)
#define SREP 32         // stat replicas

typedef short bf16x8 __attribute__((ext_vector_type(8)));
typedef float f32x4  __attribute__((ext_vector_type(4)));
typedef float f32x2  __attribute__((ext_vector_type(2)));

static __device__ __forceinline__ unsigned short f2bf(float f) {
    unsigned u = __builtin_bit_cast(unsigned, f);
    unsigned r = u + 0x7fffu + ((u >> 16) & 1u);   // round-to-nearest-even
    return (unsigned short)(r >> 16);
}
static __device__ __forceinline__ float bflo(unsigned u) {   // low bf16 -> f32
    return __builtin_bit_cast(float, u << 16);
}
static __device__ __forceinline__ float bfhi(unsigned u) {   // high bf16 -> f32
    return __builtin_bit_cast(float, u & 0xffff0000u);
}
static __device__ __forceinline__ f32x2 bf2(unsigned u) {    // {lo,hi} pair
    f32x2 r;
    r.x = bflo(u);
    r.y = bfhi(u);
    return r;
}

// --- sort pass 1: per-block bucket histogram + fused x->bf16 conversion ----
// Blocks 0..15 additionally build swizzled bf16 B for MFMA and zero the
// replicated stats (former prep_kernel):
//   Bsw[t][c][lane][j] = Wcat[t*32 + (lane>>4)*8 + j][c*16 + (lane&15)]
//   Wcat[k][d] = k<128 ? Wl[d][k] : Wr[d][k-128].
__global__ __launch_bounds__(256) void bhist_kernel(
    const int* __restrict__ dst, int* __restrict__ ghist,
    const float* __restrict__ x, unsigned short* __restrict__ xb,
    const float* __restrict__ Wl, const float* __restrict__ Wr,
    unsigned short* __restrict__ Bsw, float* __restrict__ stats,
    int E, int chunk, int NBUK, int total4) {
    __shared__ int lh[MAXBUK];
    int tid = threadIdx.x;
    int b   = blockIdx.x;
    if (b < 16) {                       // merged prep work
        int idx = b * 256 + tid;        // 0..4095
        stats[idx] = 0.f;               // 2 x 4096 = SREP*256 floats
        stats[idx + 4096] = 0.f;
        int l = idx & 63;
        int c = (idx >> 6) & 7;
        int t = idx >> 9;
        int d = c * 16 + (l & 15);
        int kbase = t * 32 + (l >> 4) * 8;
        unsigned short o[8];
#pragma unroll
        for (int j = 0; j < 8; ++j) {
            int k = kbase + j;
            float v = (k < 128) ? Wl[d * 128 + k] : Wr[d * 128 + (k - 128)];
            o[j] = f2bf(v);
        }
        *(uint4*)(Bsw + (size_t)idx * 8) = *(const uint4*)o;
    }
    for (int i = tid; i < NBUK; i += 256) lh[i] = 0;
    __syncthreads();
    int beg = b * chunk;
    int end = min(beg + chunk, E);
    for (int i = beg + tid; i < end; i += 256)
        atomicAdd(&lh[dst[i] >> BSH2], 1);
    __syncthreads();
    for (int i = tid; i < NBUK; i += 256) ghist[i * SBLK + b] = lh[i];
    // fused streaming conversion x (fp32) -> xb (bf16)
    for (int i = b * 256 + tid; i < total4; i += 256 * SBLK) {
        float4 v = ((const float4*)x)[i];
        uint2 o;
        o.x = (unsigned)f2bf(v.x) | ((unsigned)f2bf(v.y) << 16);
        o.y = (unsigned)f2bf(v.z) | ((unsigned)f2bf(v.w) << 16);
        ((uint2*)xb)[i] = o;
    }
}

// --- scan stage 1: per-block (1024 elems) partial sums ---------------------
__global__ __launch_bounds__(256) void partial_kernel(const int* __restrict__ deg,
                                                      int* __restrict__ bsum, int N) {
    int tid  = threadIdx.x;
    int base = blockIdx.x * 1024 + tid * 4;
    int s = 0;
    if (base + 3 < N) {
        int4 v = *(const int4*)(deg + base);
        s = v.x + v.y + v.z + v.w;
    } else {
        for (int i = base; i < N; ++i) s += deg[i];
    }
    __shared__ int red[256];
    red[tid] = s;
    __syncthreads();
    for (int off = 128; off > 0; off >>= 1) {
        if (tid < off) red[tid] += red[tid + off];
        __syncthreads();
    }
    if (tid == 0) bsum[blockIdx.x] = red[0];
}

// --- scan stage 2 (final): per-block scan; bsum scan via 4-per-thread ------
// Supports NB2 <= 1024: thread t serial-sums bsum[4t..4t+3], LDS-scans the
// 256 sums, then every thread reconstructs this block's exclusive base.
__global__ __launch_bounds__(256) void scan_final_kernel(
    const int* __restrict__ deg, const int* __restrict__ bsum,
    int* __restrict__ offs, int M, int NB2) {
    __shared__ int sb[2][256];
    int tid = threadIdx.x;
    int b   = blockIdx.x;

    int i0 = 4 * tid;
    int p0 = (i0     < NB2) ? bsum[i0]     : 0;
    int p1 = (i0 + 1 < NB2) ? bsum[i0 + 1] : 0;
    int p2 = (i0 + 2 < NB2) ? bsum[i0 + 2] : 0;
    int p3 = (i0 + 3 < NB2) ? bsum[i0 + 3] : 0;
    int ps = p0 + p1 + p2 + p3;
    sb[0][tid] = ps;
    __syncthreads();
    int bpi = 0;
    for (int off = 1; off < 256; off <<= 1) {
        int u = sb[bpi][tid];
        if (tid >= off) u += sb[bpi][tid - off];
        sb[bpi ^ 1][tid] = u;
        __syncthreads();
        bpi ^= 1;
    }
    int excl = sb[bpi][tid] - ps;         // exclusive over 4-groups
    __syncthreads();
    sb[0][tid] = excl;
    __syncthreads();
    int q = b >> 2, r = b & 3;
    int ebsum = sb[0][q];
    if (r > 0) ebsum += bsum[4 * q];
    if (r > 1) ebsum += bsum[4 * q + 1];
    if (r > 2) ebsum += bsum[4 * q + 2];
    __syncthreads();

    int base = b * 1024 + tid * 4;
    int d0 = 0, d1 = 0, d2 = 0, d3 = 0;
    if (base + 3 < M) {
        int4 v = *(const int4*)(deg + base);
        d0 = v.x; d1 = v.y; d2 = v.z; d3 = v.w;
    } else {
        if (base     < M) d0 = deg[base];
        if (base + 1 < M) d1 = deg[base + 1];
        if (base + 2 < M) d2 = deg[base + 2];
        if (base + 3 < M) d3 = deg[base + 3];
    }
    int s = d0 + d1 + d2 + d3;
    sb[0][tid] = s;
    __syncthreads();
    int pi = 0;
    for (int off = 1; off < 256; off <<= 1) {
        int u = sb[pi][tid];
        if (tid >= off) u += sb[pi][tid - off];
        sb[pi ^ 1][tid] = u;
        __syncthreads();
        pi ^= 1;
    }
    int pre = sb[pi][tid] - s + ebsum;
    if (base + 3 < M) {
        int4 o = make_int4(pre, pre + d0, pre + d0 + d1, pre + d0 + d1 + d2);
        *(int4*)(offs + base) = o;
    } else {
        int p = pre;
        if (base     < M) { offs[base]     = p; p += d0; }
        if (base + 1 < M) { offs[base + 1] = p; p += d1; }
        if (base + 2 < M) { offs[base + 2] = p; }
    }
}

// --- sort pass 2: scatter packed (src<<8 | dst&255) into private ranges ----
__global__ __launch_bounds__(256) void bscatter_kernel(
    const int* __restrict__ src, const int* __restrict__ dst,
    const int* __restrict__ gsc, unsigned* __restrict__ pairs,
    int E, int chunk, int NBUK) {
    __shared__ int lcur[MAXBUK];
    int tid = threadIdx.x;
    int b   = blockIdx.x;
    for (int i = tid; i < NBUK; i += 256) lcur[i] = gsc[i * SBLK + b];
    __syncthreads();
    int beg = b * chunk;
    int end = min(beg + chunk, E);
    for (int i = beg + tid; i < end; i += 256) {
        int d = dst[i];
        int s = src[i];
        int pos = atomicAdd(&lcur[d >> BSH2], 1);
        pairs[pos] = ((unsigned)s << 8) | (unsigned)(d & 255);
    }
}

// --- per-bucket: local node histogram + scan -> offs; LDS sort -> csr ------
// BSZ2=128: counters 128..255 stay zero; 256-wide scan still yields correct
// exclusive prefixes, and pre[128] == len covers the offs[bucket_end] write.
__global__ __launch_bounds__(256) void csrbuild_kernel(
    const unsigned* __restrict__ pairs, const int* __restrict__ gsc,
    int* __restrict__ csr, int* __restrict__ offs, int N, int NBUK, int E) {
    __shared__ int lcnt[256];
    __shared__ int sbuf[2][256];
    __shared__ int lcsr[CAP];
    int b   = blockIdx.x;
    int tid = threadIdx.x;
    int nlo = b << BSH2;
    int base = gsc[(size_t)b * SBLK];                       // bucket start
    int end  = (b + 1 < NBUK) ? gsc[(size_t)(b + 1) * SBLK] : E;
    int len  = end - base;
    lcnt[tid] = 0;
    __syncthreads();
    for (int i = tid; i < len; i += 256)
        atomicAdd(&lcnt[pairs[base + i] & 127u], 1);
    __syncthreads();
    int c = lcnt[tid];
    sbuf[0][tid] = c;
    __syncthreads();
    int pi = 0;
    for (int off = 1; off < 256; off <<= 1) {
        int u = sbuf[pi][tid];
        if (tid >= off) u += sbuf[pi][tid - off];
        sbuf[pi ^ 1][tid] = u;
        __syncthreads();
        pi ^= 1;
    }
    int pre = sbuf[pi][tid] - c;
    if (tid <= BSZ2 && nlo + tid <= N) offs[nlo + tid] = base + pre;
    lcnt[tid] = pre;                                        // reuse as cursor
    __syncthreads();
    if (len <= CAP) {
        for (int i = tid; i < len; i += 256) {
            unsigned p = pairs[base + i];
            int pos = atomicAdd(&lcnt[p & 127u], 1);
            lcsr[pos] = (int)(p >> 8);
        }
        __syncthreads();
        for (int i = tid; i < len; i += 256) csr[base + i] = lcsr[i];
    } else {
        for (int i = tid; i < len; i += 256) {
            unsigned p = pairs[base + i];
            int pos = atomicAdd(&lcnt[p & 127u], 1);
            csr[base + pos] = (int)(p >> 8);
        }
    }
}

// --- gather-mean from bf16 xb: aggb[n][:] = mean of xb[src] rows -----------
// Accumulates as float2 so the compiler can emit v_pk_add_f32.
__global__ __launch_bounds__(256) void gather_kernel(
    const int* __restrict__ offs, const int* __restrict__ csr,
    const unsigned short* __restrict__ xb, unsigned short* __restrict__ aggb,
    int N, int Npad) {
    int tid  = threadIdx.x;
    int l    = tid & 31;
    int half = l >> 4;
    int fl   = l & 15;
    int n    = blockIdx.x * 8 + (tid >> 5);
    if (n >= Npad) return;
    f32x2 f[4], g[4];
#pragma unroll
    for (int j = 0; j < 4; ++j) {
        f32x2 z = {0.f, 0.f};
        f[j] = z;
        g[j] = z;
    }
    float inv = 0.f;
    if (n < N) {
        int beg = offs[n], end = offs[n + 1];
        int deg = end - beg;
        int k = beg;
        for (; k + 8 <= end; k += 8) {
            int s0 = csr[k + half];
            int s1 = csr[k + 2 + half];
            int s2 = csr[k + 4 + half];
            int s3 = csr[k + 6 + half];
            uint4 v0 = *(const uint4*)(xb + (size_t)s0 * D128 + fl * 8);
            uint4 v1 = *(const uint4*)(xb + (size_t)s1 * D128 + fl * 8);
            uint4 v2 = *(const uint4*)(xb + (size_t)s2 * D128 + fl * 8);
            uint4 v3 = *(const uint4*)(xb + (size_t)s3 * D128 + fl * 8);
            f[0] += bf2(v0.x); f[1] += bf2(v0.y);
            f[2] += bf2(v0.z); f[3] += bf2(v0.w);
            g[0] += bf2(v1.x); g[1] += bf2(v1.y);
            g[2] += bf2(v1.z); g[3] += bf2(v1.w);
            f[0] += bf2(v2.x); f[1] += bf2(v2.y);
            f[2] += bf2(v2.z); f[3] += bf2(v2.w);
            g[0] += bf2(v3.x); g[1] += bf2(v3.y);
            g[2] += bf2(v3.z); g[3] += bf2(v3.w);
        }
        if (end - k >= 4) {
            int s0 = csr[k + half];
            int s1 = csr[k + 2 + half];
            uint4 v0 = *(const uint4*)(xb + (size_t)s0 * D128 + fl * 8);
            uint4 v1 = *(const uint4*)(xb + (size_t)s1 * D128 + fl * 8);
            f[0] += bf2(v0.x); f[1] += bf2(v0.y);
            f[2] += bf2(v0.z); f[3] += bf2(v0.w);
            g[0] += bf2(v1.x); g[1] += bf2(v1.y);
            g[2] += bf2(v1.z); g[3] += bf2(v1.w);
            k += 4;
        }
        if (end - k >= 2) {
            int s0 = csr[k + half];
            uint4 v0 = *(const uint4*)(xb + (size_t)s0 * D128 + fl * 8);
            f[0] += bf2(v0.x); f[1] += bf2(v0.y);
            f[2] += bf2(v0.z); f[3] += bf2(v0.w);
            k += 2;
        }
        if (k < end && half == 0) {
            int s0 = csr[k];
            uint4 v0 = *(const uint4*)(xb + (size_t)s0 * D128 + fl * 8);
            f[0] += bf2(v0.x); f[1] += bf2(v0.y);
            f[2] += bf2(v0.z); f[3] += bf2(v0.w);
        }
        if (deg > 0) inv = 1.0f / (float)deg;
    }
    float r[8];
#pragma unroll
    for (int j = 0; j < 4; ++j) {
        f[j] += g[j];
        r[2 * j]     = f[j].x;
        r[2 * j + 1] = f[j].y;
    }
#pragma unroll
    for (int j = 0; j < 8; ++j)
        r[j] += __shfl_xor(r[j], 16, 64);   // combine halves (stays in group)
    if (half == 0) {
        uint4 o;
        o.x = (unsigned)f2bf(r[0] * inv) | ((unsigned)f2bf(r[1] * inv) << 16);
        o.y = (unsigned)f2bf(r[2] * inv) | ((unsigned)f2bf(r[3] * inv) << 16);
        o.z = (unsigned)f2bf(r[4] * inv) | ((unsigned)f2bf(r[5] * inv) << 16);
        o.w = (unsigned)f2bf(r[6] * inv) | ((unsigned)f2bf(r[7] * inv) << 16);
        *(uint4*)(aggb + (size_t)n * D128 + fl * 8) = o;
    }
}

// --- MFMA dual GEMM -> bf16 h + BN stats into replicated accumulators ------
// K=256: ksteps 0-3 read aggb, 4-7 read xb. No b_l (cancelled by BN).
__global__ __launch_bounds__(256) void mfma_kernel(
    const unsigned short* __restrict__ aggb, const unsigned short* __restrict__ xb,
    const unsigned short* __restrict__ Bsw,
    unsigned short* __restrict__ h16, float* __restrict__ stats, int N) {
    __shared__ float red[4][256];
    int tid  = threadIdx.x;
    int w    = tid >> 6;
    int lane = tid & 63;
    int lc   = lane & 15;    // tile col
    int lq   = lane >> 4;    // quarter
    int rowBase = blockIdx.x * 128 + w * 32;

    f32x4 acc[2][8];
#pragma unroll
    for (int c = 0; c < 8; ++c) {
        f32x4 z = {0.f, 0.f, 0.f, 0.f};
        acc[0][c] = z;
        acc[1][c] = z;
    }
    int r0  = rowBase + lc;
    int r1  = rowBase + 16 + lc;
    int r0c = min(r0, N - 1);
    int r1c = min(r1, N - 1);
    for (int t = 0; t < 8; ++t) {
        const unsigned short* p0;
        const unsigned short* p1;
        if (t < 4) {
            int off = t * 32 + lq * 8;
            p0 = aggb + (size_t)r0 * D128 + off;
            p1 = aggb + (size_t)r1 * D128 + off;
        } else {
            int off = (t - 4) * 32 + lq * 8;
            p0 = xb + (size_t)r0c * D128 + off;
            p1 = xb + (size_t)r1c * D128 + off;
        }
        bf16x8 a0 = *(const bf16x8*)p0;
        bf16x8 a1 = *(const bf16x8*)p1;
#pragma unroll
        for (int c = 0; c < 8; ++c) {
            bf16x8 bf = *(const bf16x8*)(Bsw + ((size_t)((t * 8 + c) * 64 + lane)) * 8);
            acc[0][c] = __builtin_amdgcn_mfma_f32_16x16x32_bf16(a0, bf, acc[0][c], 0, 0, 0);
            acc[1][c] = __builtin_amdgcn_mfma_f32_16x16x32_bf16(a1, bf, acc[1][c], 0, 0, 0);
        }
    }
    float s[8], ss[8];
#pragma unroll
    for (int c = 0; c < 8; ++c) { s[c] = 0.f; ss[c] = 0.f; }
#pragma unroll
    for (int rh = 0; rh < 2; ++rh) {
#pragma unroll
        for (int reg = 0; reg < 4; ++reg) {
            int row = rowBase + rh * 16 + lq * 4 + reg;   // C-layout row
            if (row < N) {
#pragma unroll
                for (int c = 0; c < 8; ++c) {
                    float v = acc[rh][c][reg];
                    h16[(size_t)row * D128 + c * 16 + lc] = f2bf(v);
                    s[c]  += v;
                    ss[c] += v * v;
                }
            }
        }
    }
#pragma unroll
    for (int c = 0; c < 8; ++c) {
        s[c]  += __shfl_xor(s[c], 16, 64);
        s[c]  += __shfl_xor(s[c], 32, 64);
        ss[c] += __shfl_xor(ss[c], 16, 64);
        ss[c] += __shfl_xor(ss[c], 32, 64);
    }
    if (lq == 0) {
#pragma unroll
        for (int c = 0; c < 8; ++c) {
            red[w][c * 16 + lc]       = s[c];
            red[w][128 + c * 16 + lc] = ss[c];
        }
    }
    __syncthreads();
    float tot = red[0][tid] + red[1][tid] + red[2][tid] + red[3][tid];
    atomicAdd(&stats[(blockIdx.x & (SREP - 1)) * 256 + tid], tot);
}

// --- finalize: sum stat replicas, BN params in LDS, out = relu(...) --------
__global__ __launch_bounds__(256) void finalize_kernel(
    const unsigned short* __restrict__ h16, const unsigned short* __restrict__ xb,
    const float* __restrict__ stats, const float* __restrict__ gamma,
    const float* __restrict__ beta, float* __restrict__ out,
    long long total4, float invN) {
    __shared__ float sscl[D128];
    __shared__ float sshf[D128];
    int tid = threadIdx.x;
    if (tid < D128) {
        float sum = 0.f, sq = 0.f;
#pragma unroll
        for (int r = 0; r < SREP; ++r) {
            sum += stats[r * 256 + tid];
            sq  += stats[r * 256 + 128 + tid];
        }
        float mean = sum * invN;
        float var  = sq * invN - mean * mean;
        float istd = rsqrtf(var + 1e-5f);
        float sc   = gamma[tid] * istd;
        sscl[tid] = sc;
        sshf[tid] = beta[tid] - mean * sc;
    }
    __syncthreads();
    long long i = (long long)blockIdx.x * 256 + tid;
    if (i >= total4) return;
    int d = (int)((i * 4) & 127);
    uint2 hv = ((const uint2*)h16)[i];
    uint2 xv = ((const uint2*)xb)[i];
    float4 o;
    o.x = fmaxf(fmaf(bflo(hv.x), sscl[d],     sshf[d])     + bflo(xv.x), 0.f);
    o.y = fmaxf(fmaf(bfhi(hv.x), sscl[d + 1], sshf[d + 1]) + bfhi(xv.x), 0.f);
    o.z = fmaxf(fmaf(bflo(hv.y), sscl[d + 2], sshf[d + 2]) + bflo(xv.y), 0.f);
    o.w = fmaxf(fmaf(bfhi(hv.y), sscl[d + 3], sshf[d + 3]) + bfhi(xv.y), 0.f);
    ((float4*)out)[i] = o;
}

extern "C" void kernel_launch(void* const* d_in, const int* in_sizes, int n_in,
                              void* d_out, int out_size, void* d_ws, size_t ws_size,
                              hipStream_t stream) {
    const float* x     = (const float*)d_in[0];
    const int*   eidx  = (const int*)d_in[1];
    const float* W_l   = (const float*)d_in[2];
    const float* W_r   = (const float*)d_in[4];
    const float* gamma = (const float*)d_in[5];
    const float* beta  = (const float*)d_in[6];

    const int D = in_sizes[3];            // 128
    const int N = in_sizes[0] / D;        // 100000
    const int E = in_sizes[1] / 2;        // 1600000

    const int* src = eidx;
    const int* dst = eidx + E;

    const int NBLK  = (N + 127) / 128;        // mfma blocks (782)
    const int Npad  = NBLK * 128;             // padded rows (100096)
    const int NBUK  = (N + BSZ2 - 1) / BSZ2;  // buckets (782)
    const int M     = NBUK * SBLK;            // ghist cells (400384)
    const int NB2   = (M + 1023) / 1024;      // scan blocks (391, <=1024)
    const int chunk = (E + SBLK - 1) / SBLK;  // edges per sort block (3125)
    const int total4 = N * D128 / 4;          // float4s in x

    // workspace layout (byte cursor, 64B-aligned chunks)
    char* wp = (char*)d_ws;
    auto alloc = [&](size_t bytes) {
        char* p = wp;
        wp += (bytes + 63) & ~(size_t)63;
        return p;
    };
    float*    stats = (float*)   alloc((size_t)SREP * 256 * 4);
    int*      offs  = (int*)     alloc((size_t)(N + 1) * 4);
    int*      csr   = (int*)     alloc((size_t)E * 4);
    unsigned* pairs = (unsigned*)alloc((size_t)E * 4);
    int*      ghist = (int*)     alloc((size_t)M * 4);
    int*      gsc   = (int*)     alloc((size_t)(M + 1) * 4);
    int*      bsum  = (int*)     alloc(1024 * 4);
    unsigned short* Bsw  = (unsigned short*)alloc(4096 * 16);
    unsigned short* xb   = (unsigned short*)alloc((size_t)N * D128 * 2);
    unsigned short* aggb = (unsigned short*)alloc((size_t)Npad * D128 * 2);
    unsigned short* h16  = (unsigned short*)alloc((size_t)N * D128 * 2);

    float* outp = (float*)d_out;
    float invN = 1.0f / (float)N;

    // bucket hist (+ fused x->bf16 + prep) -> scan -> block-private scatter
    bhist_kernel<<<SBLK, 256, 0, stream>>>(dst, ghist, x, xb, W_l, W_r, Bsw,
                                           stats, E, chunk, NBUK, total4);
    partial_kernel<<<NB2, 256, 0, stream>>>(ghist, bsum, M);
    scan_final_kernel<<<NB2, 256, 0, stream>>>(ghist, bsum, gsc, M, NB2);
    bscatter_kernel<<<SBLK, 256, 0, stream>>>(src, dst, gsc, pairs, E, chunk, NBUK);

    // per-bucket CSR build (also writes offs)
    csrbuild_kernel<<<NBUK, 256, 0, stream>>>(pairs, gsc, csr, offs, N, NBUK, E);

    gather_kernel<<<Npad / 8, 256, 0, stream>>>(offs, csr, xb, aggb, N, Npad);

    mfma_kernel<<<NBLK, 256, 0, stream>>>(aggb, xb, Bsw, h16, stats, N);

    {
        long long t4 = (long long)N * D128 / 4;
        finalize_kernel<<<(int)((t4 + 255) / 256), 256, 0, stream>>>(
            h16, xb, stats, gamma, beta, outp, t4, invN);
    }
}